// Round 1
// baseline (749.821 us; speedup 1.0000x reference)
//
#include <hip/hip_runtime.h>

#define NN 20000
#define EE 320000
#define RATIO_F 0.18257418583505536f   // 1/sqrt(30)
#define EPS_F 1e-6f
#define SCALE_D4 0.35355339059327373f  // 64^-0.25

__device__ __forceinline__ unsigned fenc(float x) {
  unsigned u = __float_as_uint(x);
  return (u & 0x80000000u) ? ~u : (u | 0x80000000u);
}
__device__ __forceinline__ float fdec(unsigned u) {
  return (u & 0x80000000u) ? __uint_as_float(u & 0x7FFFFFFFu) : __uint_as_float(~u);
}
__device__ __forceinline__ void fma4(float* a, float s, float4 b) {
  a[0] = fmaf(s, b.x, a[0]);
  a[1] = fmaf(s, b.y, a[1]);
  a[2] = fmaf(s, b.z, a[2]);
  a[3] = fmaf(s, b.w, a[3]);
}

// ------------- K0: build fused weight matrix WT[256 k][1024 cols] + bias -------------
// cols: [0,256)=q  [256,512)=k  [512,640)=xd_q(120+8pad)  [640,768)=xd_k  [768,1024)=v
__global__ __launch_bounds__(256)
void k0_build(const float* __restrict__ Wq, const float* __restrict__ Wk,
              const float* __restrict__ Wv, const float* __restrict__ bq,
              const float* __restrict__ bk, const float* __restrict__ bv,
              const float* __restrict__ proj, const float* __restrict__ tau,
              float* __restrict__ WT, float* __restrict__ bbig) {
  const int col = blockIdx.x;
  const int i = threadIdx.x;
  const float s = rsqrtf(tau[0]) * SCALE_D4;
  float val = 0.f, bias = 0.f;
  if (col < 256) {
    val = Wq[col * 256 + i]; bias = bq[col];
  } else if (col < 512) {
    const int c = col - 256;
    val = Wk[c * 256 + i]; bias = bk[c];
  } else if (col < 768) {
    const int hm = (col < 640) ? (col - 512) : (col - 640);
    if (hm < 120) {
      const float* W = (col < 640) ? Wq : Wk;
      const float* bb = (col < 640) ? bq : bk;
      const int hh = hm / 30, m = hm - hh * 30;
      float a = 0.f, ba = 0.f;
#pragma unroll 8
      for (int d = 0; d < 64; ++d) {
        const float pr = proj[m * 64 + d];
        a  = fmaf(pr, W[(hh * 64 + d) * 256 + i], a);
        ba = fmaf(pr, bb[hh * 64 + d], ba);
      }
      val = s * a; bias = s * ba;
    }
  } else {
    const int c = col - 768;
    val = Wv[c * 256 + i]; bias = bv[c];
  }
  WT[i * 1024 + col] = val;
  if (i == 0) bbig[col] = bias;
}

// ------------- K1: fused GEMM (q,k,xd_q,xd_k,v) + feature-map epilogues -------------
__global__ __launch_bounds__(256, 2)
void k1_main(const float* __restrict__ feat, const float* __restrict__ zin,
             const float* __restrict__ WT, const float* __restrict__ bbig,
             const float* __restrict__ tau,
             float* __restrict__ qp, float* __restrict__ kbuf,
             float* __restrict__ vbuf, unsigned* __restrict__ kmaxU) {
  __shared__ float Alds[32 * 260];   // 32 rows x 256 K, padded
  __shared__ float Bx[32 * 132];     // B-tile during GEMM / xd buffer in epilogue
  __shared__ float diagq[32][4];
  __shared__ float diagk[32][4];

  const int t = threadIdx.x;
  const int tx = t & 31, ty = t >> 5;
  const int c0 = tx * 4, r0 = ty * 4;
  const int n0 = blockIdx.x * 32;
  const float s = rsqrtf(tau[0]) * SCALE_D4;
  const float h2 = 0.5f * s * s;

  {
    const float* src = feat + (size_t)n0 * 256;
#pragma unroll
    for (int l = 0; l < 8; ++l) {
      const int flat = l * 1024 + t * 4;
      *(float4*)&Alds[(flat >> 8) * 260 + (flat & 255)] = *(const float4*)(src + flat);
    }
  }
  __syncthreads();

  for (int ct = 0; ct < 8; ++ct) {
    if (ct == 6) {  // restage A with z for the v columns
      __syncthreads();
      const float* src = zin + (size_t)n0 * 256;
#pragma unroll
      for (int l = 0; l < 8; ++l) {
        const int flat = l * 1024 + t * 4;
        *(float4*)&Alds[(flat >> 8) * 260 + (flat & 255)] = *(const float4*)(src + flat);
      }
      __syncthreads();
    }
    float acc[4][4];
#pragma unroll
    for (int j = 0; j < 4; ++j) { acc[j][0] = 0.f; acc[j][1] = 0.f; acc[j][2] = 0.f; acc[j][3] = 0.f; }

    for (int kc = 0; kc < 8; ++kc) {
      __syncthreads();
      {
        const int kk = t >> 3, cb = (t & 7) * 16;
        const float* srcw = WT + (size_t)(kc * 32 + kk) * 1024 + ct * 128 + cb;
#pragma unroll
        for (int j = 0; j < 4; ++j)
          *(float4*)&Bx[kk * 132 + cb + j * 4] = *(const float4*)(srcw + j * 4);
      }
      __syncthreads();
      const int ko = kc * 32;
#pragma unroll
      for (int ku = 0; ku < 8; ++ku) {
        const int kb = ko + ku * 4;
        const float4 a0 = *(const float4*)&Alds[(r0 + 0) * 260 + kb];
        const float4 a1 = *(const float4*)&Alds[(r0 + 1) * 260 + kb];
        const float4 a2 = *(const float4*)&Alds[(r0 + 2) * 260 + kb];
        const float4 a3 = *(const float4*)&Alds[(r0 + 3) * 260 + kb];
        const float4 b0 = *(const float4*)&Bx[(ku * 4 + 0) * 132 + c0];
        const float4 b1 = *(const float4*)&Bx[(ku * 4 + 1) * 132 + c0];
        const float4 b2 = *(const float4*)&Bx[(ku * 4 + 2) * 132 + c0];
        const float4 b3 = *(const float4*)&Bx[(ku * 4 + 3) * 132 + c0];
        fma4(acc[0], a0.x, b0); fma4(acc[0], a0.y, b1); fma4(acc[0], a0.z, b2); fma4(acc[0], a0.w, b3);
        fma4(acc[1], a1.x, b0); fma4(acc[1], a1.y, b1); fma4(acc[1], a1.z, b2); fma4(acc[1], a1.w, b3);
        fma4(acc[2], a2.x, b0); fma4(acc[2], a2.y, b1); fma4(acc[2], a2.z, b2); fma4(acc[2], a2.w, b3);
        fma4(acc[3], a3.x, b0); fma4(acc[3], a3.y, b1); fma4(acc[3], a3.z, b2); fma4(acc[3], a3.w, b3);
      }
    }
    {
      const float4 bb = *(const float4*)(bbig + ct * 128 + c0);
#pragma unroll
      for (int j = 0; j < 4; ++j) {
        acc[j][0] += bb.x; acc[j][1] += bb.y; acc[j][2] += bb.z; acc[j][3] += bb.w;
      }
    }

    if (ct < 4) {
      // diag = 0.5*s^2 * sum_d q^2 : reduce 16 lanes (one head = 16 lanes x 4 cols)
      float ss[4];
#pragma unroll
      for (int j = 0; j < 4; ++j)
        ss[j] = acc[j][0] * acc[j][0] + acc[j][1] * acc[j][1] +
                acc[j][2] * acc[j][2] + acc[j][3] * acc[j][3];
#pragma unroll
      for (int off = 1; off < 16; off <<= 1) {
#pragma unroll
        for (int j = 0; j < 4; ++j) ss[j] += __shfl_xor(ss[j], off, 64);
      }
      if ((tx & 15) == 0) {
        const int head = (ct & 1) * 2 + (tx >> 4);
        float (*dst)[4] = (ct < 2) ? diagq : diagk;
#pragma unroll
        for (int j = 0; j < 4; ++j) dst[r0 + j][head] = h2 * ss[j];
      }
    } else if (ct < 6) {
      __syncthreads();  // everyone done reading Bx as B-tile
#pragma unroll
      for (int j = 0; j < 4; ++j) {
        float4 o = make_float4(acc[j][0], acc[j][1], acc[j][2], acc[j][3]);
        *(float4*)&Bx[(r0 + j) * 132 + c0] = o;
      }
      __syncthreads();
      if (t < 128) {
        const int r = t >> 2, hh = t & 3;
        float* row = &Bx[r * 132 + hh * 30];
        float mx = row[0];
#pragma unroll
        for (int m = 1; m < 30; ++m) mx = fmaxf(mx, row[m]);
        if (ct == 4) {
          const float dgv = diagq[r][hh];
#pragma unroll
          for (int m = 0; m < 30; ++m)
            row[m] = RATIO_F * (expf(row[m] - dgv - mx) + EPS_F);
        } else {
          atomicMax(&kmaxU[hh], fenc(mx));
          const float dgv = diagk[r][hh];
#pragma unroll
          for (int m = 0; m < 30; ++m) row[m] -= dgv;
        }
      }
      __syncthreads();
      float* gdst = (ct == 4) ? qp : kbuf;
#pragma unroll
      for (int l = 0; l < 15; ++l) {
        const int flat = l * 256 + t;
        const int r = flat / 120;
        const int cc = flat - r * 120;
        gdst[(size_t)(n0 + r) * 120 + cc] = Bx[r * 132 + cc];
      }
    } else {
      const int cbase = (ct - 6) * 128 + c0;
#pragma unroll
      for (int j = 0; j < 4; ++j) {
        float4 o = make_float4(acc[j][0], acc[j][1], acc[j][2], acc[j][3]);
        *(float4*)(vbuf + (size_t)(n0 + r0 + j) * 256 + cbase) = o;
      }
    }
  }
}

// ------------- K2: finalize kp = ratio*(exp(kxd - kmax[h]) + eps), in place -------------
__global__ __launch_bounds__(256)
void k2_kp(float* __restrict__ kbuf, const unsigned* __restrict__ kmaxU) {
  const int idx = blockIdx.x * 256 + threadIdx.x;  // grid exact: N*120
  const int hh = (idx % 120) / 30;
  const float mx = fdec(kmaxU[hh]);
  kbuf[idx] = RATIO_F * (expf(kbuf[idx] - mx) + EPS_F);
}

// ------------- K3: kvs[h,m,d] = sum_n kp[n,h,m]*v[n,h,d]; ksum[h,m] = sum_n kp -------------
__global__ __launch_bounds__(256)
void k3_kvs(const float* __restrict__ kp, const float* __restrict__ v,
            float* __restrict__ kvs, float* __restrict__ ksum) {
  __shared__ float kpch[128 * 32];
  __shared__ float vch[128 * 68];
  const int h = blockIdx.y;
  const int n0 = blockIdx.x * 128;
  const int cnt = min(128, NN - n0);
  const int t = threadIdx.x;
  const int m = t >> 3, dg = t & 7, d0 = dg * 8;
#pragma unroll
  for (int l = 0; l < 15; ++l) {
    const int flat = l * 256 + t;
    const int nl = flat / 30, mm = flat - nl * 30;
    kpch[nl * 32 + mm] = (nl < cnt) ? kp[(size_t)(n0 + nl) * 120 + h * 30 + mm] : 0.f;
  }
#pragma unroll
  for (int l = 0; l < 8; ++l) {
    const int f4 = l * 256 + t;
    const int nl = f4 >> 4, dd = (f4 & 15) * 4;
    float4 vv = make_float4(0.f, 0.f, 0.f, 0.f);
    if (nl < cnt) vv = *(const float4*)(v + (size_t)(n0 + nl) * 256 + h * 64 + dd);
    *(float4*)&vch[nl * 68 + dd] = vv;
  }
  __syncthreads();
  float acc[8] = {0, 0, 0, 0, 0, 0, 0, 0};
  float asum = 0.f;
  const int ms = (m < 30) ? m : 0;
  for (int nl = 0; nl < cnt; ++nl) {
    const float kv = kpch[nl * 32 + ms];
    const float4 va = *(const float4*)&vch[nl * 68 + d0];
    const float4 vb = *(const float4*)&vch[nl * 68 + d0 + 4];
    fma4(&acc[0], kv, va);
    fma4(&acc[4], kv, vb);
    asum += kv;
  }
  if (m < 30) {
    float* dst = kvs + (size_t)(h * 30 + m) * 64 + d0;
#pragma unroll
    for (int j = 0; j < 8; ++j) atomicAdd(dst + j, acc[j]);
    if (dg == 0) atomicAdd(ksum + h * 30 + m, asum);
  }
}

// ------------- K4: num/den -> zbuf[n, h*64+d] -------------
__global__ __launch_bounds__(256)
void k4_attn(const float* __restrict__ qp, const float* __restrict__ kvs,
             const float* __restrict__ ksum, float* __restrict__ zbuf) {
  __shared__ float kvsl[120 * 68];
  __shared__ float ksl[120];
  __shared__ float qpl[32 * 120];
  const int t = threadIdx.x;
  const int n0 = blockIdx.x * 32;
#pragma unroll
  for (int l = 0; l < 30; ++l) {
    const int f = l * 256 + t;           // 7680
    const int hm = f >> 6, d = f & 63;
    kvsl[hm * 68 + d] = kvs[f];
  }
  if (t < 120) ksl[t] = ksum[t];
#pragma unroll
  for (int l = 0; l < 15; ++l) {
    const int f = l * 256 + t;           // 3840
    qpl[f] = qp[(size_t)n0 * 120 + f];
  }
  __syncthreads();
  const int nl = t >> 3, dg = t & 7, d0 = dg * 8;
  const float* qrow = &qpl[nl * 120];
  float den[4] = {0, 0, 0, 0};
  for (int m = 0; m < 30; ++m) {
#pragma unroll
    for (int hh = 0; hh < 4; ++hh) den[hh] = fmaf(qrow[hh * 30 + m], ksl[hh * 30 + m], den[hh]);
  }
  float acc[4][8] = {};
  for (int m = 0; m < 30; ++m) {
#pragma unroll
    for (int hh = 0; hh < 4; ++hh) {
      const float qv = qrow[hh * 30 + m];
      const float* kr = &kvsl[(hh * 30 + m) * 68 + d0];
      const float4 ka = *(const float4*)kr;
      const float4 kb = *(const float4*)(kr + 4);
      fma4(&acc[hh][0], qv, ka);
      fma4(&acc[hh][4], qv, kb);
    }
  }
  const size_t n = n0 + nl;
#pragma unroll
  for (int hh = 0; hh < 4; ++hh) {
    const float inv = 1.0f / den[hh];
    float4 o1 = make_float4(acc[hh][0] * inv, acc[hh][1] * inv, acc[hh][2] * inv, acc[hh][3] * inv);
    float4 o2 = make_float4(acc[hh][4] * inv, acc[hh][5] * inv, acc[hh][6] * inv, acc[hh][7] * inv);
    *(float4*)(zbuf + n * 256 + hh * 64 + d0) = o1;
    *(float4*)(zbuf + n * 256 + hh * 64 + d0 + 4) = o2;
  }
}

// ------------- K5: degree counts -------------
__global__ __launch_bounds__(256)
void k5_deg(const int* __restrict__ ei, int* __restrict__ dini, int* __restrict__ douti) {
  const int e = blockIdx.x * 256 + threadIdx.x;  // grid exact
  atomicAdd(&dini[ei[EE + e]], 1);   // col
  atomicAdd(&douti[ei[e]], 1);       // row
}

// ------------- K6a: exclusive scan of in-degrees -> csr offsets (single block) -------------
__global__ __launch_bounds__(256)
void k6a_scan(const int* __restrict__ cnt, int* __restrict__ off) {
  __shared__ int s[256];
  const int t = threadIdx.x;
  int lo = t * 79; if (lo > NN) lo = NN;
  int hi = lo + 79; if (hi > NN) hi = NN;
  int sum = 0;
  for (int i = lo; i < hi; ++i) sum += cnt[i];
  s[t] = sum;
  __syncthreads();
  for (int o = 1; o < 256; o <<= 1) {
    const int add = (t >= o) ? s[t - o] : 0;
    __syncthreads();
    s[t] += add;
    __syncthreads();
  }
  int run = (t == 0) ? 0 : s[t - 1];
  if (t == 0) off[0] = 0;
  for (int i = lo; i < hi; ++i) { run += cnt[i]; off[i + 1] = run; }
}

// ------------- K6b: fill CSR (rows bucketed by col) -------------
__global__ __launch_bounds__(256)
void k6b_fill(const int* __restrict__ ei, const int* __restrict__ coff,
              int* __restrict__ cursor, int* __restrict__ crow) {
  const int e = blockIdx.x * 256 + threadIdx.x;
  const int r = ei[e], c = ei[EE + e];
  const int pos = atomicAdd(&cursor[c], 1);
  crow[coff[c] + pos] = r;
}

// ------------- K7: gather-aggregate relational bias, zbuf += sigmoid(b)*agg -------------
__global__ __launch_bounds__(256)
void k7_gather(const int* __restrict__ coff, const int* __restrict__ crow,
               const int* __restrict__ douti, const float* __restrict__ vbuf,
               const float* __restrict__ bp, float* __restrict__ zbuf) {
  const int n = blockIdx.x;
  const int c = threadIdx.x;
  const int o0 = coff[n], o1 = coff[n + 1];
  float acc = 0.f;
  if (o1 > o0) {
    const float rin = rsqrtf((float)(o1 - o0));
    for (int e = o0; e < o1; ++e) {
      const int r = crow[e];
      const float w = rin * rsqrtf((float)douti[r]);
      acc = fmaf(w, vbuf[(size_t)r * 256 + c], acc);
    }
  }
  const float sb = 1.f / (1.f + expf(-bp[c >> 6]));
  zbuf[(size_t)n * 256 + c] += sb * acc;
}

// ------------- K8: out = zbuf @ Wo^T + bo  (c-split x2, Wo half staged in LDS) -------------
__global__ __launch_bounds__(256)
void k8_out(const float* __restrict__ zbuf, const float* __restrict__ Wo,
            const float* __restrict__ bo, float* __restrict__ out) {
  __shared__ float WoT[256 * 33];
  __shared__ float zbl[8 * 256];
  const int t = threadIdx.x;
  const int ch = blockIdx.y;  // 0/1 -> output cols [ch*32, ch*32+32)
#pragma unroll
  for (int l = 0; l < 32; ++l) {
    WoT[t * 33 + l] = Wo[(ch * 32 + l) * 256 + t];
  }
  const int nl = t >> 5, cp = t & 31;
  const float bias = bo[ch * 32 + cp];
  for (int g = blockIdx.x; g < 2500; g += gridDim.x) {
    __syncthreads();
#pragma unroll
    for (int l = 0; l < 2; ++l) {
      const int f4 = l * 256 + t;       // 512 float4 = 2048 floats = 8 rows
      *(float4*)&zbl[f4 * 4] = *(const float4*)(zbuf + (size_t)g * 2048 + f4 * 4);
    }
    __syncthreads();
    float acc = bias;
#pragma unroll
    for (int i4 = 0; i4 < 64; ++i4) {
      const float4 z4 = *(const float4*)&zbl[nl * 256 + i4 * 4];
      acc = fmaf(z4.x, WoT[(i4 * 4 + 0) * 33 + cp], acc);
      acc = fmaf(z4.y, WoT[(i4 * 4 + 1) * 33 + cp], acc);
      acc = fmaf(z4.z, WoT[(i4 * 4 + 2) * 33 + cp], acc);
      acc = fmaf(z4.w, WoT[(i4 * 4 + 3) * 33 + cp], acc);
    }
    out[((size_t)g * 8 + nl) * 64 + ch * 32 + cp] = acc;
  }
}

extern "C" void kernel_launch(void* const* d_in, const int* in_sizes, int n_in,
                              void* d_out, int out_size, void* d_ws, size_t ws_size,
                              hipStream_t stream) {
  (void)in_sizes; (void)n_in; (void)out_size; (void)ws_size;
  const float* z    = (const float*)d_in[0];
  const float* feat = (const float*)d_in[1];
  const int*   ei   = (const int*)d_in[2];
  const float* tau  = (const float*)d_in[3];
  const float* Wq_w = (const float*)d_in[4];
  const float* Wq_b = (const float*)d_in[5];
  const float* Wk_w = (const float*)d_in[6];
  const float* Wk_b = (const float*)d_in[7];
  const float* Wv_w = (const float*)d_in[8];
  const float* Wv_b = (const float*)d_in[9];
  const float* Wo_w = (const float*)d_in[10];
  const float* Wo_b = (const float*)d_in[11];
  const float* bp   = (const float*)d_in[12];
  const float* proj = (const float*)d_in[13];
  float* out = (float*)d_out;

  char* p = (char*)d_ws;
  auto alloc = [&](size_t bytes) { char* r = p; p += (bytes + 255) & ~(size_t)255; return r; };
  float*    WT    = (float*)alloc((size_t)256 * 1024 * 4);
  float*    bbig  = (float*)alloc(1024 * 4);
  float*    vbuf  = (float*)alloc((size_t)NN * 256 * 4);
  float*    qp    = (float*)alloc((size_t)NN * 120 * 4);
  float*    kbuf  = (float*)alloc((size_t)NN * 120 * 4);
  float*    zbuf  = (float*)alloc((size_t)NN * 256 * 4);
  float*    kvs   = (float*)alloc(7680 * 4);
  float*    ksum  = (float*)alloc(120 * 4);
  unsigned* kmaxU = (unsigned*)alloc(16);
  int*      dini  = (int*)alloc((size_t)NN * 4);
  int*      douti = (int*)alloc((size_t)NN * 4);
  int*      cursor= (int*)alloc((size_t)NN * 4);
  int*      coff  = (int*)alloc((size_t)(NN + 1) * 4);
  int*      crow  = (int*)alloc((size_t)EE * 4);

  hipMemsetAsync(kvs, 0, 7680 * 4, stream);
  hipMemsetAsync(ksum, 0, 120 * 4, stream);
  hipMemsetAsync(kmaxU, 0, 16, stream);
  hipMemsetAsync(dini, 0, (size_t)NN * 4, stream);
  hipMemsetAsync(douti, 0, (size_t)NN * 4, stream);
  hipMemsetAsync(cursor, 0, (size_t)NN * 4, stream);

  k0_build<<<1024, 256, 0, stream>>>(Wq_w, Wk_w, Wv_w, Wq_b, Wk_b, Wv_b, proj, tau, WT, bbig);
  k5_deg<<<EE / 256, 256, 0, stream>>>(ei, dini, douti);
  k6a_scan<<<1, 256, 0, stream>>>(dini, coff);
  k6b_fill<<<EE / 256, 256, 0, stream>>>(ei, coff, cursor, crow);
  k1_main<<<NN / 32, 256, 0, stream>>>(feat, z, WT, bbig, tau, qp, kbuf, vbuf, kmaxU);
  k2_kp<<<(NN * 120) / 256, 256, 0, stream>>>(kbuf, kmaxU);
  k3_kvs<<<dim3((NN + 127) / 128, 4), 256, 0, stream>>>(kbuf, vbuf, kvs, ksum);
  k4_attn<<<NN / 32, 256, 0, stream>>>(qp, kvs, ksum, zbuf);
  k7_gather<<<NN, 256, 0, stream>>>(coff, crow, douti, vbuf, bp, zbuf);
  k8_out<<<dim3(512, 2), 256, 0, stream>>>(zbuf, Wo_w, Wo_b, out);
}

// Round 2
// 516.887 us; speedup vs baseline: 1.4506x; 1.4506x over previous
//
#include <hip/hip_runtime.h>

#define NN 20000
#define EE 320000
#define RATIO_F 0.18257418583505536f   // 1/sqrt(30)
#define EPS_F 1e-6f
#define SCALE_D4 0.35355339059327373f  // 64^-0.25

typedef __bf16 bf16x8 __attribute__((ext_vector_type(8)));
typedef float f32x4 __attribute__((ext_vector_type(4)));
typedef unsigned short ushort_t;

__device__ __forceinline__ unsigned fenc(float x) {
  unsigned u = __float_as_uint(x);
  return (u & 0x80000000u) ? ~u : (u | 0x80000000u);
}
__device__ __forceinline__ float fdec(unsigned u) {
  return (u & 0x80000000u) ? __uint_as_float(u & 0x7FFFFFFFu) : __uint_as_float(~u);
}
__device__ __forceinline__ void fma4(float* a, float s, float4 b) {
  a[0] = fmaf(s, b.x, a[0]);
  a[1] = fmaf(s, b.y, a[1]);
  a[2] = fmaf(s, b.z, a[2]);
  a[3] = fmaf(s, b.w, a[3]);
}
__device__ __forceinline__ ushort_t bfrnd(float f) {  // f32 -> bf16 bits, RNE
  unsigned u = __float_as_uint(f);
  return (ushort_t)((u + 0x7FFFu + ((u >> 16) & 1u)) >> 16);
}

// =====================================================================
// K0: build fused weight planes in MFMA B-fragment order (hi/lo bf16).
// Column layout (1024): [0,256)=q  [256,512)=k  [512,768)=v
//                       [768,896)=xd_q (4 heads x 32, m<30 valid)
//                       [896,1024)=xd_k
// Fragment order: frag fi = ctile*8 + ktile, 512 bf16 each; within frag,
// lane l (= g*16 + cl) element j holds W[k=32*kt+8*g+j][col=ct*16+cl].
// =====================================================================
__global__ __launch_bounds__(256)
void k0_build(const float* __restrict__ Wq, const float* __restrict__ Wk,
              const float* __restrict__ Wv, const float* __restrict__ bq,
              const float* __restrict__ bk, const float* __restrict__ bv,
              const float* __restrict__ proj, const float* __restrict__ tau,
              ushort_t* __restrict__ Wh, ushort_t* __restrict__ Wl,
              float* __restrict__ bbig) {
  const int col = blockIdx.x;
  const int i = threadIdx.x;   // k index
  const float s = rsqrtf(tau[0]) * SCALE_D4;
  float val = 0.f, bias = 0.f;
  if (col < 256) {
    val = Wq[col * 256 + i]; bias = bq[col];
  } else if (col < 512) {
    const int c = col - 256;
    val = Wk[c * 256 + i]; bias = bk[c];
  } else if (col < 768) {
    const int c = col - 512;
    val = Wv[c * 256 + i]; bias = bv[c];
  } else {
    const int rr = col - 768;
    const int grp = rr >> 7;             // 0 = q, 1 = k
    const int h = (rr >> 5) & 3, m = rr & 31;
    if (m < 30) {
      const float* W = grp ? Wk : Wq;
      const float* bb = grp ? bk : bq;
      float a = 0.f, ba = 0.f;
#pragma unroll 8
      for (int d = 0; d < 64; ++d) {
        const float pr = proj[m * 64 + d];
        a  = fmaf(pr, W[(h * 64 + d) * 256 + i], a);
        ba = fmaf(pr, bb[h * 64 + d], ba);
      }
      val = s * a; bias = s * ba;
    }
  }
  const int kt = i >> 5, gg = (i >> 3) & 3, j = i & 7;
  const int lane = gg * 16 + (col & 15);
  const size_t off = (size_t)((col >> 4) * 8 + kt) * 512 + lane * 8 + j;
  const ushort_t hb = bfrnd(val);
  Wh[off] = hb;
  Wl[off] = bfrnd(val - __uint_as_float(((unsigned)hb) << 16));
  if (i == 0) bbig[col] = bias;
}

// ---- A-fragment loader: 16 rows x 256 K of f32 -> hi/lo bf16 frags ----
__device__ __forceinline__ void load_frags(const float* __restrict__ p, int g,
                                           bf16x8* Ah, bf16x8* Al) {
#pragma unroll
  for (int kt = 0; kt < 8; ++kt) {
    const float4 f0 = *(const float4*)(p + kt * 32 + g * 8);
    const float4 f1 = *(const float4*)(p + kt * 32 + g * 8 + 4);
    float ff[8] = {f0.x, f0.y, f0.z, f0.w, f1.x, f1.y, f1.z, f1.w};
    union { ushort_t s[8]; bf16x8 v; } hu, lu;
#pragma unroll
    for (int j = 0; j < 8; ++j) {
      const ushort_t hb = bfrnd(ff[j]);
      hu.s[j] = hb;
      lu.s[j] = bfrnd(ff[j] - __uint_as_float(((unsigned)hb) << 16));
    }
    Ah[kt] = hu.v; Al[kt] = lu.v;
  }
}

// ---- one 16x16 C-tile over full K=256, 3-term bf16 split ----
__device__ __forceinline__ f32x4 mfma3(const ushort_t* __restrict__ Wh,
                                       const ushort_t* __restrict__ Wl,
                                       int ct, int lane,
                                       const bf16x8* Ah, const bf16x8* Al) {
  const ushort_t* bhp = Wh + (size_t)ct * 4096 + lane * 8;
  const ushort_t* blp = Wl + (size_t)ct * 4096 + lane * 8;
  bf16x8 bh[8], bl[8];
#pragma unroll
  for (int kt = 0; kt < 8; ++kt) {
    bh[kt] = *(const bf16x8*)(bhp + kt * 512);
    bl[kt] = *(const bf16x8*)(blp + kt * 512);
  }
  f32x4 P = {0.f, 0.f, 0.f, 0.f}, Q = {0.f, 0.f, 0.f, 0.f}, R = {0.f, 0.f, 0.f, 0.f};
#pragma unroll
  for (int kt = 0; kt < 8; ++kt) {
    P = __builtin_amdgcn_mfma_f32_16x16x32_bf16(Ah[kt], bh[kt], P, 0, 0, 0);
    Q = __builtin_amdgcn_mfma_f32_16x16x32_bf16(Ah[kt], bl[kt], Q, 0, 0, 0);
    R = __builtin_amdgcn_mfma_f32_16x16x32_bf16(Al[kt], bh[kt], R, 0, 0, 0);
  }
  return P + Q + R;
}

// =====================================================================
// K1: MFMA GEMM (20000 x 1024 x 256) + fused feature-map epilogues.
// Block = 32 rows, 4 waves: w0/w1 = q,k (diag), w2/w3 = v then xd.
// =====================================================================
__global__ __launch_bounds__(256, 2)
void k1_mfma(const float* __restrict__ feat, const float* __restrict__ zin,
             const ushort_t* __restrict__ Wh, const ushort_t* __restrict__ Wl,
             const float* __restrict__ bbig, const float* __restrict__ tau,
             float* __restrict__ qp, float* __restrict__ kbuf,
             float* __restrict__ vbuf, unsigned* __restrict__ kmaxU) {
  __shared__ float dlds[32][2][4];   // [row][q/k][head]
  const int t = threadIdx.x;
  const int w = t >> 6, lane = t & 63;
  const int g = lane >> 4, cl = lane & 15;
  const int s = w & 1, ch = w >> 1;
  const int n0 = blockIdx.x * 32;
  const int rowbase = n0 + 16 * s;
  const int myrow = rowbase + cl;
  const float sc = rsqrtf(tau[0]) * SCALE_D4;
  const float h2 = 0.5f * sc * sc;
  bf16x8 Ah[8], Al[8];

  if (ch == 0) {
    // ---------------- q,k tiles -> diag ----------------
    load_frags(feat + (size_t)myrow * 256, g, Ah, Al);
    for (int hg = 0; hg < 8; ++hg) {     // 4 q-heads then 4 k-heads
      float ds[4] = {0.f, 0.f, 0.f, 0.f};
      for (int c4 = 0; c4 < 4; ++c4) {
        const int ct = hg * 4 + c4;
        f32x4 a = mfma3(Wh, Wl, ct, lane, Ah, Al);
        const float bb = bbig[ct * 16 + cl];
#pragma unroll
        for (int j = 0; j < 4; ++j) {
          const float vv = a[j] + bb;
          ds[j] = fmaf(vv, vv, ds[j]);
        }
      }
#pragma unroll
      for (int m = 1; m < 16; m <<= 1) {
#pragma unroll
        for (int j = 0; j < 4; ++j) ds[j] += __shfl_xor(ds[j], m);
      }
      if (cl == 0) {
        const int qk = hg >> 2, h = hg & 3;
#pragma unroll
        for (int j = 0; j < 4; ++j) dlds[16 * s + 4 * g + j][qk][h] = h2 * ds[j];
      }
    }
  } else {
    // ---------------- v tiles (A = z) ----------------
    load_frags(zin + (size_t)myrow * 256, g, Ah, Al);
    for (int ct = 32; ct < 48; ++ct) {
      f32x4 a = mfma3(Wh, Wl, ct, lane, Ah, Al);
      const float bb = bbig[ct * 16 + cl];
      const int c = (ct - 32) * 16 + cl;
#pragma unroll
      for (int j = 0; j < 4; ++j)
        vbuf[(size_t)(rowbase + 4 * g + j) * 256 + c] = a[j] + bb;
    }
    load_frags(feat + (size_t)myrow * 256, g, Ah, Al);  // for xd
  }
  __syncthreads();
  if (ch == 1) {
    // ---------------- xd tiles -> qp / kbuf ----------------
    for (int pair = 0; pair < 8; ++pair) {
      const int qk = pair >> 2, h = pair & 3;
      const int ct0 = 48 + pair * 2;
      f32x4 a0 = mfma3(Wh, Wl, ct0, lane, Ah, Al);
      f32x4 a1 = mfma3(Wh, Wl, ct0 + 1, lane, Ah, Al);
      const float b0 = bbig[ct0 * 16 + cl];
      const float b1 = bbig[ct0 * 16 + 16 + cl];
      float rmax[4];
#pragma unroll
      for (int j = 0; j < 4; ++j) {
        a0[j] += b0; a1[j] += b1;
        float mv = fmaxf(a0[j], (cl < 14) ? a1[j] : -3.4e38f);
#pragma unroll
        for (int m = 1; m < 16; m <<= 1) mv = fmaxf(mv, __shfl_xor(mv, m));
        rmax[j] = mv;
      }
      if (qk == 0) {
#pragma unroll
        for (int j = 0; j < 4; ++j) {
          const float dg = dlds[16 * s + 4 * g + j][0][h];
          const int r = rowbase + 4 * g + j;
          float* dst = qp + (size_t)r * 120 + h * 30;
          dst[cl] = RATIO_F * (expf(a0[j] - dg - rmax[j]) + EPS_F);
          if (cl < 14)
            dst[16 + cl] = RATIO_F * (expf(a1[j] - dg - rmax[j]) + EPS_F);
        }
      } else {
        float wm = fmaxf(fmaxf(rmax[0], rmax[1]), fmaxf(rmax[2], rmax[3]));
        wm = fmaxf(wm, __shfl_xor(wm, 16));
        wm = fmaxf(wm, __shfl_xor(wm, 32));
        if (lane == 0) atomicMax(&kmaxU[h], fenc(wm));
#pragma unroll
        for (int j = 0; j < 4; ++j) {
          const float dg = dlds[16 * s + 4 * g + j][1][h];
          const int r = rowbase + 4 * g + j;
          float* dst = kbuf + (size_t)r * 120 + h * 30;
          dst[cl] = a0[j] - dg;
          if (cl < 14) dst[16 + cl] = a1[j] - dg;
        }
      }
    }
  }
}

// ------------- K2: finalize kp = ratio*(exp(kxd - kmax[h]) + eps), in place -------------
__global__ __launch_bounds__(256)
void k2_kp(float* __restrict__ kbuf, const unsigned* __restrict__ kmaxU) {
  const int idx = blockIdx.x * 256 + threadIdx.x;  // grid exact: N*120
  const int hh = (idx % 120) / 30;
  const float mx = fdec(kmaxU[hh]);
  kbuf[idx] = RATIO_F * (expf(kbuf[idx] - mx) + EPS_F);
}

// ------------- K3: kvs[h,m,d] = sum_n kp[n,h,m]*v[n,h,d]; ksum[h,m] = sum_n kp -------------
__global__ __launch_bounds__(256)
void k3_kvs(const float* __restrict__ kp, const float* __restrict__ v,
            float* __restrict__ kvs, float* __restrict__ ksum) {
  __shared__ float kpch[128 * 32];
  __shared__ float vch[128 * 68];
  const int h = blockIdx.y;
  const int n0 = blockIdx.x * 128;
  const int cnt = min(128, NN - n0);
  const int t = threadIdx.x;
  const int m = t >> 3, dg = t & 7, d0 = dg * 8;
#pragma unroll
  for (int l = 0; l < 15; ++l) {
    const int flat = l * 256 + t;
    const int nl = flat / 30, mm = flat - nl * 30;
    kpch[nl * 32 + mm] = (nl < cnt) ? kp[(size_t)(n0 + nl) * 120 + h * 30 + mm] : 0.f;
  }
#pragma unroll
  for (int l = 0; l < 8; ++l) {
    const int f4 = l * 256 + t;
    const int nl = f4 >> 4, dd = (f4 & 15) * 4;
    float4 vv = make_float4(0.f, 0.f, 0.f, 0.f);
    if (nl < cnt) vv = *(const float4*)(v + (size_t)(n0 + nl) * 256 + h * 64 + dd);
    *(float4*)&vch[nl * 68 + dd] = vv;
  }
  __syncthreads();
  float acc[8] = {0, 0, 0, 0, 0, 0, 0, 0};
  float asum = 0.f;
  const int ms = (m < 30) ? m : 0;
  for (int nl = 0; nl < cnt; ++nl) {
    const float kv = kpch[nl * 32 + ms];
    const float4 va = *(const float4*)&vch[nl * 68 + d0];
    const float4 vb = *(const float4*)&vch[nl * 68 + d0 + 4];
    fma4(&acc[0], kv, va);
    fma4(&acc[4], kv, vb);
    asum += kv;
  }
  if (m < 30) {
    float* dst = kvs + (size_t)(h * 30 + m) * 64 + d0;
#pragma unroll
    for (int j = 0; j < 8; ++j) atomicAdd(dst + j, acc[j]);
    if (dg == 0) atomicAdd(ksum + h * 30 + m, asum);
  }
}

// ------------- K4: num/den -> zbuf[n, h*64+d] -------------
__global__ __launch_bounds__(256)
void k4_attn(const float* __restrict__ qp, const float* __restrict__ kvs,
             const float* __restrict__ ksum, float* __restrict__ zbuf) {
  __shared__ float kvsl[120 * 68];
  __shared__ float ksl[120];
  __shared__ float qpl[32 * 120];
  const int t = threadIdx.x;
  const int n0 = blockIdx.x * 32;
#pragma unroll
  for (int l = 0; l < 30; ++l) {
    const int f = l * 256 + t;           // 7680
    const int hm = f >> 6, d = f & 63;
    kvsl[hm * 68 + d] = kvs[f];
  }
  if (t < 120) ksl[t] = ksum[t];
#pragma unroll
  for (int l = 0; l < 15; ++l) {
    const int f = l * 256 + t;           // 3840
    qpl[f] = qp[(size_t)n0 * 120 + f];
  }
  __syncthreads();
  const int nl = t >> 3, dg = t & 7, d0 = dg * 8;
  const float* qrow = &qpl[nl * 120];
  float den[4] = {0, 0, 0, 0};
  for (int m = 0; m < 30; ++m) {
#pragma unroll
    for (int hh = 0; hh < 4; ++hh) den[hh] = fmaf(qrow[hh * 30 + m], ksl[hh * 30 + m], den[hh]);
  }
  float acc[4][8] = {};
  for (int m = 0; m < 30; ++m) {
#pragma unroll
    for (int hh = 0; hh < 4; ++hh) {
      const float qv = qrow[hh * 30 + m];
      const float* kr = &kvsl[(hh * 30 + m) * 68 + d0];
      const float4 ka = *(const float4*)kr;
      const float4 kb = *(const float4*)(kr + 4);
      fma4(&acc[hh][0], qv, ka);
      fma4(&acc[hh][4], qv, kb);
    }
  }
  const size_t n = n0 + nl;
#pragma unroll
  for (int hh = 0; hh < 4; ++hh) {
    const float inv = 1.0f / den[hh];
    float4 o1 = make_float4(acc[hh][0] * inv, acc[hh][1] * inv, acc[hh][2] * inv, acc[hh][3] * inv);
    float4 o2 = make_float4(acc[hh][4] * inv, acc[hh][5] * inv, acc[hh][6] * inv, acc[hh][7] * inv);
    *(float4*)(zbuf + n * 256 + hh * 64 + d0) = o1;
    *(float4*)(zbuf + n * 256 + hh * 64 + d0 + 4) = o2;
  }
}

// ------------- K5: degree counts -------------
__global__ __launch_bounds__(256)
void k5_deg(const int* __restrict__ ei, int* __restrict__ dini, int* __restrict__ douti) {
  const int e = blockIdx.x * 256 + threadIdx.x;  // grid exact
  atomicAdd(&dini[ei[EE + e]], 1);   // col
  atomicAdd(&douti[ei[e]], 1);       // row
}

// ------------- K6a: exclusive scan of in-degrees -> csr offsets (single block) -------------
__global__ __launch_bounds__(256)
void k6a_scan(const int* __restrict__ cnt, int* __restrict__ off) {
  __shared__ int s[256];
  const int t = threadIdx.x;
  int lo = t * 79; if (lo > NN) lo = NN;
  int hi = lo + 79; if (hi > NN) hi = NN;
  int sum = 0;
  for (int i = lo; i < hi; ++i) sum += cnt[i];
  s[t] = sum;
  __syncthreads();
  for (int o = 1; o < 256; o <<= 1) {
    const int add = (t >= o) ? s[t - o] : 0;
    __syncthreads();
    s[t] += add;
    __syncthreads();
  }
  int run = (t == 0) ? 0 : s[t - 1];
  if (t == 0) off[0] = 0;
  for (int i = lo; i < hi; ++i) { run += cnt[i]; off[i + 1] = run; }
}

// ------------- K6b: fill CSR (rows bucketed by col) -------------
__global__ __launch_bounds__(256)
void k6b_fill(const int* __restrict__ ei, const int* __restrict__ coff,
              int* __restrict__ cursor, int* __restrict__ crow) {
  const int e = blockIdx.x * 256 + threadIdx.x;
  const int r = ei[e], c = ei[EE + e];
  const int pos = atomicAdd(&cursor[c], 1);
  crow[coff[c] + pos] = r;
}

// ------------- K7: gather-aggregate relational bias, zbuf += sigmoid(b)*agg -------------
__global__ __launch_bounds__(256)
void k7_gather(const int* __restrict__ coff, const int* __restrict__ crow,
               const int* __restrict__ douti, const float* __restrict__ vbuf,
               const float* __restrict__ bp, float* __restrict__ zbuf) {
  const int n = blockIdx.x;
  const int c = threadIdx.x;
  const int o0 = coff[n], o1 = coff[n + 1];
  float acc = 0.f;
  if (o1 > o0) {
    const float rin = rsqrtf((float)(o1 - o0));
    for (int e = o0; e < o1; ++e) {
      const int r = crow[e];
      const float w = rin * rsqrtf((float)douti[r]);
      acc = fmaf(w, vbuf[(size_t)r * 256 + c], acc);
    }
  }
  const float sb = 1.f / (1.f + expf(-bp[c >> 6]));
  zbuf[(size_t)n * 256 + c] += sb * acc;
}

// ------------- K8: out = zbuf @ Wo^T + bo  (c-split x2, Wo half staged in LDS) -------------
__global__ __launch_bounds__(256)
void k8_out(const float* __restrict__ zbuf, const float* __restrict__ Wo,
            const float* __restrict__ bo, float* __restrict__ out) {
  __shared__ float WoT[256 * 33];
  __shared__ float zbl[8 * 256];
  const int t = threadIdx.x;
  const int ch = blockIdx.y;  // 0/1 -> output cols [ch*32, ch*32+32)
#pragma unroll
  for (int l = 0; l < 32; ++l) {
    WoT[t * 33 + l] = Wo[(ch * 32 + l) * 256 + t];
  }
  const int nl = t >> 5, cp = t & 31;
  const float bias = bo[ch * 32 + cp];
  for (int g = blockIdx.x; g < 2500; g += gridDim.x) {
    __syncthreads();
#pragma unroll
    for (int l = 0; l < 2; ++l) {
      const int f4 = l * 256 + t;       // 512 float4 = 2048 floats = 8 rows
      *(float4*)&zbl[f4 * 4] = *(const float4*)(zbuf + (size_t)g * 2048 + f4 * 4);
    }
    __syncthreads();
    float acc = bias;
#pragma unroll
    for (int i4 = 0; i4 < 64; ++i4) {
      const float4 z4 = *(const float4*)&zbl[nl * 256 + i4 * 4];
      acc = fmaf(z4.x, WoT[(i4 * 4 + 0) * 33 + cp], acc);
      acc = fmaf(z4.y, WoT[(i4 * 4 + 1) * 33 + cp], acc);
      acc = fmaf(z4.z, WoT[(i4 * 4 + 2) * 33 + cp], acc);
      acc = fmaf(z4.w, WoT[(i4 * 4 + 3) * 33 + cp], acc);
    }
    out[((size_t)g * 8 + nl) * 64 + ch * 32 + cp] = acc;
  }
}

extern "C" void kernel_launch(void* const* d_in, const int* in_sizes, int n_in,
                              void* d_out, int out_size, void* d_ws, size_t ws_size,
                              hipStream_t stream) {
  (void)in_sizes; (void)n_in; (void)out_size; (void)ws_size;
  const float* z    = (const float*)d_in[0];
  const float* feat = (const float*)d_in[1];
  const int*   ei   = (const int*)d_in[2];
  const float* tau  = (const float*)d_in[3];
  const float* Wq_w = (const float*)d_in[4];
  const float* Wq_b = (const float*)d_in[5];
  const float* Wk_w = (const float*)d_in[6];
  const float* Wk_b = (const float*)d_in[7];
  const float* Wv_w = (const float*)d_in[8];
  const float* Wv_b = (const float*)d_in[9];
  const float* Wo_w = (const float*)d_in[10];
  const float* Wo_b = (const float*)d_in[11];
  const float* bp   = (const float*)d_in[12];
  const float* proj = (const float*)d_in[13];
  float* out = (float*)d_out;

  char* p = (char*)d_ws;
  auto alloc = [&](size_t bytes) { char* r = p; p += (bytes + 255) & ~(size_t)255; return r; };
  ushort_t* Wh    = (ushort_t*)alloc((size_t)256 * 1024 * 2);
  ushort_t* Wl    = (ushort_t*)alloc((size_t)256 * 1024 * 2);
  float*    bbig  = (float*)alloc(1024 * 4);
  float*    vbuf  = (float*)alloc((size_t)NN * 256 * 4);
  float*    qp    = (float*)alloc((size_t)NN * 120 * 4);
  float*    kbuf  = (float*)alloc((size_t)NN * 120 * 4);
  float*    zbuf  = (float*)alloc((size_t)NN * 256 * 4);
  float*    kvs   = (float*)alloc(7680 * 4);
  float*    ksum  = (float*)alloc(120 * 4);
  unsigned* kmaxU = (unsigned*)alloc(16);
  int*      dini  = (int*)alloc((size_t)NN * 4);
  int*      douti = (int*)alloc((size_t)NN * 4);
  int*      cursor= (int*)alloc((size_t)NN * 4);
  int*      coff  = (int*)alloc((size_t)(NN + 1) * 4);
  int*      crow  = (int*)alloc((size_t)EE * 4);

  hipMemsetAsync(kvs, 0, 7680 * 4, stream);
  hipMemsetAsync(ksum, 0, 120 * 4, stream);
  hipMemsetAsync(kmaxU, 0, 16, stream);
  hipMemsetAsync(dini, 0, (size_t)NN * 4, stream);
  hipMemsetAsync(douti, 0, (size_t)NN * 4, stream);
  hipMemsetAsync(cursor, 0, (size_t)NN * 4, stream);

  k0_build<<<1024, 256, 0, stream>>>(Wq_w, Wk_w, Wv_w, Wq_b, Wk_b, Wv_b, proj, tau, Wh, Wl, bbig);
  k5_deg<<<EE / 256, 256, 0, stream>>>(ei, dini, douti);
  k6a_scan<<<1, 256, 0, stream>>>(dini, coff);
  k6b_fill<<<EE / 256, 256, 0, stream>>>(ei, coff, cursor, crow);
  k1_mfma<<<NN / 32, 256, 0, stream>>>(feat, z, Wh, Wl, bbig, tau, qp, kbuf, vbuf, kmaxU);
  k2_kp<<<(NN * 120) / 256, 256, 0, stream>>>(kbuf, kmaxU);
  k3_kvs<<<dim3((NN + 127) / 128, 4), 256, 0, stream>>>(kbuf, vbuf, kvs, ksum);
  k4_attn<<<NN / 32, 256, 0, stream>>>(qp, kvs, ksum, zbuf);
  k7_gather<<<NN, 256, 0, stream>>>(coff, crow, douti, vbuf, bp, zbuf);
  k8_out<<<dim3(512, 2), 256, 0, stream>>>(zbuf, Wo_w, Wo_b, out);
}

// Round 3
// 465.295 us; speedup vs baseline: 1.6115x; 1.1109x over previous
//
#include <hip/hip_runtime.h>

#define NN 20000
#define EE 320000
#define RATIO_F 0.18257418583505536f   // 1/sqrt(30)
#define EPS_F 1e-6f
#define SCALE_D4 0.35355339059327373f  // 64^-0.25

typedef __bf16 bf16x8 __attribute__((ext_vector_type(8)));
typedef float f32x4 __attribute__((ext_vector_type(4)));
typedef unsigned short ushort_t;

__device__ __forceinline__ unsigned fenc(float x) {
  unsigned u = __float_as_uint(x);
  return (u & 0x80000000u) ? ~u : (u | 0x80000000u);
}
__device__ __forceinline__ float fdec(unsigned u) {
  return (u & 0x80000000u) ? __uint_as_float(u & 0x7FFFFFFFu) : __uint_as_float(~u);
}
__device__ __forceinline__ void fma4(float* a, float s, float4 b) {
  a[0] = fmaf(s, b.x, a[0]);
  a[1] = fmaf(s, b.y, a[1]);
  a[2] = fmaf(s, b.z, a[2]);
  a[3] = fmaf(s, b.w, a[3]);
}
__device__ __forceinline__ ushort_t bfrnd(float f) {  // f32 -> bf16 bits, RNE
  unsigned u = __float_as_uint(f);
  return (ushort_t)((u + 0x7FFFu + ((u >> 16) & 1u)) >> 16);
}
__device__ __forceinline__ float b2f(ushort_t u) {
  return __uint_as_float(((unsigned)u) << 16);
}

// =====================================================================
// K0: build fused weight planes in MFMA B-fragment order (hi/lo bf16).
// Column layout (1024): [0,256)=q  [256,512)=k  [512,768)=v
//                       [768,896)=xd_q (4 heads x 32, m<30 valid)
//                       [896,1024)=xd_k
// Fragment: fi = ct*8 + kt (512 bf16); lane l=(g*16+cl), elem j holds
// W[k=32*kt+8*g+j][col=ct*16+cl].
// =====================================================================
__global__ __launch_bounds__(256)
void k0_build(const float* __restrict__ Wq, const float* __restrict__ Wk,
              const float* __restrict__ Wv, const float* __restrict__ bq,
              const float* __restrict__ bk, const float* __restrict__ bv,
              const float* __restrict__ proj, const float* __restrict__ tau,
              ushort_t* __restrict__ Wh, ushort_t* __restrict__ Wl,
              float* __restrict__ bbig) {
  const int col = blockIdx.x;
  const int i = threadIdx.x;   // k index
  const float s = rsqrtf(tau[0]) * SCALE_D4;
  float val = 0.f, bias = 0.f;
  if (col < 256) {
    val = Wq[col * 256 + i]; bias = bq[col];
  } else if (col < 512) {
    const int c = col - 256;
    val = Wk[c * 256 + i]; bias = bk[c];
  } else if (col < 768) {
    const int c = col - 512;
    val = Wv[c * 256 + i]; bias = bv[c];
  } else {
    const int rr = col - 768;
    const int grp = rr >> 7;             // 0 = q, 1 = k
    const int h = (rr >> 5) & 3, m = rr & 31;
    if (m < 30) {
      const float* W = grp ? Wk : Wq;
      const float* bb = grp ? bk : bq;
      float a = 0.f, ba = 0.f;
#pragma unroll 8
      for (int d = 0; d < 64; ++d) {
        const float pr = proj[m * 64 + d];
        a  = fmaf(pr, W[(h * 64 + d) * 256 + i], a);
        ba = fmaf(pr, bb[h * 64 + d], ba);
      }
      val = s * a; bias = s * ba;
    }
  }
  const int kt = i >> 5, gg = (i >> 3) & 3, j = i & 7;
  const int lane = gg * 16 + (col & 15);
  const size_t off = (size_t)((col >> 4) * 8 + kt) * 512 + lane * 8 + j;
  const ushort_t hb = bfrnd(val);
  Wh[off] = hb;
  Wl[off] = bfrnd(val - __uint_as_float(((unsigned)hb) << 16));
  if (i == 0) bbig[col] = bias;
}

// ---- A-fragment loader: 16 rows x 256 K of f32 -> hi/lo bf16 frags ----
__device__ __forceinline__ void load_frags(const float* __restrict__ p, int g,
                                           bf16x8* Ah, bf16x8* Al) {
#pragma unroll
  for (int kt = 0; kt < 8; ++kt) {
    const float4 f0 = *(const float4*)(p + kt * 32 + g * 8);
    const float4 f1 = *(const float4*)(p + kt * 32 + g * 8 + 4);
    float ff[8] = {f0.x, f0.y, f0.z, f0.w, f1.x, f1.y, f1.z, f1.w};
    union { ushort_t s[8]; bf16x8 v; } hu, lu;
#pragma unroll
    for (int j = 0; j < 8; ++j) {
      const ushort_t hb = bfrnd(ff[j]);
      hu.s[j] = hb;
      lu.s[j] = bfrnd(ff[j] - __uint_as_float(((unsigned)hb) << 16));
    }
    Ah[kt] = hu.v; Al[kt] = lu.v;
  }
}

// =====================================================================
// K1: MFMA GEMM (20000 x 1024 x 256) + fused feature-map epilogues.
// 157 blocks x 4 waves; wave owns 32 rows (2 row-tiles), sweeps 64 cts.
// B double-buffered in LDS (2 cts = 32KB per buffer), reg-staged.
// Phase order p=0..31 (2 cts each): q(0-7), k(8-15), xd(16-23), v(24-31).
// =====================================================================
__global__ __launch_bounds__(256, 1)
void k1_mfma(const float* __restrict__ feat, const float* __restrict__ zin,
             const ushort_t* __restrict__ Wh, const ushort_t* __restrict__ Wl,
             const float* __restrict__ bbig, const float* __restrict__ tau,
             float* __restrict__ qp, float* __restrict__ kbuf,
             ushort_t* __restrict__ vb16, unsigned* __restrict__ kmaxU) {
  __shared__ ushort_t bstage[2][16384];   // [buf][ct0 hi|ct1 hi|ct0 lo|ct1 lo] 8KB each
  __shared__ float dlds[4][2][4][32];     // [wave][q/k][head][row-in-wave]
  const int t = threadIdx.x;
  const int wid = t >> 6, lane = t & 63;
  const int g = lane >> 4, cl = lane & 15;
  const int n0 = blockIdx.x * 128 + wid * 32;
  const float sc = rsqrtf(tau[0]) * SCALE_D4;
  const float h2 = 0.5f * sc * sc;

  bf16x8 Ah[2][8], Al[2][8];
#pragma unroll
  for (int rt = 0; rt < 2; ++rt) {
    int r = n0 + rt * 16 + cl; if (r > NN - 1) r = NN - 1;
    load_frags(feat + (size_t)r * 256, g, Ah[rt], Al[rt]);
  }

  // prologue: stage phase-0 group (cts 0,1)
#pragma unroll
  for (int s8 = 0; s8 < 8; ++s8) {
    const int idx = s8 * 256 + t;
    const ushort_t* src = (idx < 1024) ? (Wh + idx * 8) : (Wl + (size_t)(idx - 1024) * 8);
    *(uint4*)&bstage[0][idx * 8] = *(const uint4*)src;
  }
  __syncthreads();

  float dsA[2][4];
  f32x4 a0s[2];

  for (int p = 0; p < 32; ++p) {
    const int cur = p & 1;
    const int ctb = (p < 16) ? (p * 2) : (p < 24) ? (48 + (p - 16) * 2) : (32 + (p - 24) * 2);
    uint4 stg[8];
    const int pn = p + 1;
    if (pn < 32) {
      const int ctn = (pn < 16) ? (pn * 2) : (pn < 24) ? (48 + (pn - 16) * 2) : (32 + (pn - 24) * 2);
      const size_t base = (size_t)ctn * 4096;
#pragma unroll
      for (int s8 = 0; s8 < 8; ++s8) {
        const int idx = s8 * 256 + t;
        const ushort_t* src = (idx < 1024) ? (Wh + base + idx * 8)
                                           : (Wl + base + (size_t)(idx - 1024) * 8);
        stg[s8] = *(const uint4*)src;
      }
    }
    if (p == 24) {  // switch A to z for the v column phases
#pragma unroll
      for (int rt = 0; rt < 2; ++rt) {
        int r = n0 + rt * 16 + cl; if (r > NN - 1) r = NN - 1;
        load_frags(zin + (size_t)r * 256, g, Ah[rt], Al[rt]);
      }
    }
    float wmax = -3.4e38f;
#pragma unroll
    for (int c = 0; c < 2; ++c) {
      const int ct = ctb + c;
      bf16x8 bh[8], bl[8];
#pragma unroll
      for (int kt = 0; kt < 8; ++kt) {
        bh[kt] = *(const bf16x8*)&bstage[cur][c * 4096 + kt * 512 + lane * 8];
        bl[kt] = *(const bf16x8*)&bstage[cur][8192 + c * 4096 + kt * 512 + lane * 8];
      }
      const float bb = bbig[ct * 16 + cl];
#pragma unroll
      for (int rt = 0; rt < 2; ++rt) {
        f32x4 P = {0.f, 0.f, 0.f, 0.f}, Q = {0.f, 0.f, 0.f, 0.f}, R = {0.f, 0.f, 0.f, 0.f};
#pragma unroll
        for (int kt = 0; kt < 8; ++kt) {
          P = __builtin_amdgcn_mfma_f32_16x16x32_bf16(Ah[rt][kt], bh[kt], P, 0, 0, 0);
          Q = __builtin_amdgcn_mfma_f32_16x16x32_bf16(Ah[rt][kt], bl[kt], Q, 0, 0, 0);
          R = __builtin_amdgcn_mfma_f32_16x16x32_bf16(Al[rt][kt], bh[kt], R, 0, 0, 0);
        }
        f32x4 a;
#pragma unroll
        for (int j = 0; j < 4; ++j) a[j] = P[j] + Q[j] + R[j] + bb;

        if (p < 16) {
          // ---- q/k: accumulate row sum-of-squares over the head's 4 cts ----
          const int qk = p >> 3, h = (p >> 1) & 3;
          const int sub = ((p & 1) << 1) + c;
#pragma unroll
          for (int j = 0; j < 4; ++j) {
            const float vv = a[j];
            if (sub == 0) dsA[rt][j] = vv * vv;
            else dsA[rt][j] = fmaf(vv, vv, dsA[rt][j]);
          }
          if (sub == 3) {
#pragma unroll
            for (int j = 0; j < 4; ++j) {
              float v2 = dsA[rt][j];
#pragma unroll
              for (int m = 1; m < 16; m <<= 1) v2 += __shfl_xor(v2, m);
              if (cl == 0) dlds[wid][qk][h][rt * 16 + 4 * g + j] = h2 * v2;
            }
          }
        } else if (p < 24) {
          // ---- xd: pair (c=0: m 0-15, c=1: m 16-29) -> softmax-kernel ----
          if (c == 0) {
            a0s[rt] = a;
          } else {
            const int qk = (p - 16) >> 2, h = (p - 16) & 3;
#pragma unroll
            for (int j = 0; j < 4; ++j) {
              const float m0 = a0s[rt][j], m1 = a[j];
              float mv = fmaxf(m0, (cl < 14) ? m1 : -3.4e38f);
#pragma unroll
              for (int m = 1; m < 16; m <<= 1) mv = fmaxf(mv, __shfl_xor(mv, m));
              const float dg = dlds[wid][qk][h][rt * 16 + 4 * g + j];
              const int r = n0 + rt * 16 + 4 * g + j;
              if (qk == 0) {
                if (r < NN) {
                  float* dst = qp + (size_t)r * 120 + h * 30;
                  dst[cl] = RATIO_F * (expf(m0 - dg - mv) + EPS_F);
                  if (cl < 14) dst[16 + cl] = RATIO_F * (expf(m1 - dg - mv) + EPS_F);
                }
              } else {
                wmax = fmaxf(wmax, mv);
                if (r < NN) {
                  float* dst = kbuf + (size_t)r * 120 + h * 30;
                  dst[cl] = m0 - dg;
                  if (cl < 14) dst[16 + cl] = m1 - dg;
                }
              }
            }
          }
        } else {
          // ---- v: bias + bf16 store ----
          const int colb = (ct - 32) * 16 + cl;
#pragma unroll
          for (int j = 0; j < 4; ++j) {
            const int r = n0 + rt * 16 + 4 * g + j;
            if (r < NN) vb16[(size_t)r * 256 + colb] = bfrnd(a[j]);
          }
        }
      }
    }
    if (p >= 20 && p < 24) {   // xd_k phase for head p-20: global k-max
      wmax = fmaxf(wmax, __shfl_xor(wmax, 16));
      wmax = fmaxf(wmax, __shfl_xor(wmax, 32));
      if (lane == 0) atomicMax(&kmaxU[p - 20], fenc(wmax));
    }
    __syncthreads();
    if (pn < 32) {
#pragma unroll
      for (int s8 = 0; s8 < 8; ++s8)
        *(uint4*)&bstage[cur ^ 1][(s8 * 256 + t) * 8] = stg[s8];
    }
    __syncthreads();
  }
}

// ------------- K3: kvs[h,m,d] = sum_n kp*v; ksum[h,m] = sum_n kp (kp inline) -------------
__global__ __launch_bounds__(256)
void k3_kvs(const float* __restrict__ kbr, const ushort_t* __restrict__ vb16,
            const unsigned* __restrict__ kmaxU,
            float* __restrict__ kvs, float* __restrict__ ksum) {
  __shared__ float kpch[128 * 32];
  __shared__ float vch[128 * 68];
  const int h = blockIdx.y;
  const int n0 = blockIdx.x * 128;
  const int cnt = min(128, NN - n0);
  const int t = threadIdx.x;
  const float mx = fdec(kmaxU[h]);
  const int m = t >> 3, dg = t & 7, d0 = dg * 8;
#pragma unroll
  for (int l = 0; l < 15; ++l) {
    const int flat = l * 256 + t;
    const int nl = flat / 30, mm = flat - nl * 30;
    kpch[nl * 32 + mm] = (nl < cnt)
        ? RATIO_F * (expf(kbr[(size_t)(n0 + nl) * 120 + h * 30 + mm] - mx) + EPS_F)
        : 0.f;
  }
#pragma unroll
  for (int l = 0; l < 8; ++l) {
    const int f4 = l * 256 + t;
    const int nl = f4 >> 4, dd = (f4 & 15) * 4;
    float4 vv = make_float4(0.f, 0.f, 0.f, 0.f);
    if (nl < cnt) {
      ushort4 u = *(const ushort4*)(vb16 + (size_t)(n0 + nl) * 256 + h * 64 + dd);
      vv = make_float4(b2f(u.x), b2f(u.y), b2f(u.z), b2f(u.w));
    }
    *(float4*)&vch[nl * 68 + dd] = vv;
  }
  __syncthreads();
  float acc[8] = {0, 0, 0, 0, 0, 0, 0, 0};
  float asum = 0.f;
  const int ms = (m < 30) ? m : 0;
  for (int nl = 0; nl < cnt; ++nl) {
    const float kv = kpch[nl * 32 + ms];
    const float4 va = *(const float4*)&vch[nl * 68 + d0];
    const float4 vb = *(const float4*)&vch[nl * 68 + d0 + 4];
    fma4(&acc[0], kv, va);
    fma4(&acc[4], kv, vb);
    asum += kv;
  }
  if (m < 30) {
    float* dst = kvs + (size_t)(h * 30 + m) * 64 + d0;
#pragma unroll
    for (int j = 0; j < 8; ++j) atomicAdd(dst + j, acc[j]);
    if (dg == 0) atomicAdd(ksum + h * 30 + m, asum);
  }
}

// ------------- K4: num/den -> zbuf[n, h*64+d] -------------
__global__ __launch_bounds__(256)
void k4_attn(const float* __restrict__ qp, const float* __restrict__ kvs,
             const float* __restrict__ ksum, float* __restrict__ zbuf) {
  __shared__ float kvsl[120 * 68];
  __shared__ float ksl[120];
  __shared__ float qpl[32 * 120];
  const int t = threadIdx.x;
  const int n0 = blockIdx.x * 32;
#pragma unroll
  for (int l = 0; l < 30; ++l) {
    const int f = l * 256 + t;           // 7680
    const int hm = f >> 6, d = f & 63;
    kvsl[hm * 68 + d] = kvs[f];
  }
  if (t < 120) ksl[t] = ksum[t];
#pragma unroll
  for (int l = 0; l < 15; ++l) {
    const int f = l * 256 + t;           // 3840
    qpl[f] = qp[(size_t)n0 * 120 + f];
  }
  __syncthreads();
  const int nl = t >> 3, dg = t & 7, d0 = dg * 8;
  const float* qrow = &qpl[nl * 120];
  float den[4] = {0, 0, 0, 0};
  for (int m = 0; m < 30; ++m) {
#pragma unroll
    for (int hh = 0; hh < 4; ++hh) den[hh] = fmaf(qrow[hh * 30 + m], ksl[hh * 30 + m], den[hh]);
  }
  float acc[4][8] = {};
  for (int m = 0; m < 30; ++m) {
#pragma unroll
    for (int hh = 0; hh < 4; ++hh) {
      const float qv = qrow[hh * 30 + m];
      const float* kr = &kvsl[(hh * 30 + m) * 68 + d0];
      const float4 ka = *(const float4*)kr;
      const float4 kb = *(const float4*)(kr + 4);
      fma4(&acc[hh][0], qv, ka);
      fma4(&acc[hh][4], qv, kb);
    }
  }
  const size_t n = n0 + nl;
#pragma unroll
  for (int hh = 0; hh < 4; ++hh) {
    const float inv = 1.0f / den[hh];
    float4 o1 = make_float4(acc[hh][0] * inv, acc[hh][1] * inv, acc[hh][2] * inv, acc[hh][3] * inv);
    float4 o2 = make_float4(acc[hh][4] * inv, acc[hh][5] * inv, acc[hh][6] * inv, acc[hh][7] * inv);
    *(float4*)(zbuf + n * 256 + hh * 64 + d0) = o1;
    *(float4*)(zbuf + n * 256 + hh * 64 + d0 + 4) = o2;
  }
}

// ------------- K5: degree counts (int4 vectorized) -------------
__global__ __launch_bounds__(256)
void k5_deg(const int* __restrict__ ei, int* __restrict__ dini, int* __restrict__ douti) {
  const int q = blockIdx.x * 256 + threadIdx.x;
  if (q >= EE / 4) return;
  const int4 r4 = *(const int4*)(ei + q * 4);
  const int4 c4 = *(const int4*)(ei + EE + q * 4);
  atomicAdd(&dini[c4.x], 1); atomicAdd(&dini[c4.y], 1);
  atomicAdd(&dini[c4.z], 1); atomicAdd(&dini[c4.w], 1);
  atomicAdd(&douti[r4.x], 1); atomicAdd(&douti[r4.y], 1);
  atomicAdd(&douti[r4.z], 1); atomicAdd(&douti[r4.w], 1);
}

// ------------- K6a: exclusive scan of in-degrees (1024 threads, int4) -------------
__global__ __launch_bounds__(1024)
void k6a_scan(const int* __restrict__ cnt, int* __restrict__ off) {
  __shared__ int s[1024];
  const int t = threadIdx.x;
  int4 v[5];
  int sum = 0;
  const int4* p4 = (const int4*)(cnt + t * 20);
#pragma unroll
  for (int i = 0; i < 5; ++i) {
    v[i] = p4[i];
    sum += v[i].x + v[i].y + v[i].z + v[i].w;
  }
  s[t] = sum;
  __syncthreads();
  for (int o = 1; o < 1024; o <<= 1) {
    const int add = (t >= o) ? s[t - o] : 0;
    __syncthreads();
    s[t] += add;
    __syncthreads();
  }
  int run = (t == 0) ? 0 : s[t - 1];
  if (t == 0) off[0] = 0;
  const int base = t * 20;
#pragma unroll
  for (int i = 0; i < 5; ++i) {
    const int vals[4] = {v[i].x, v[i].y, v[i].z, v[i].w};
#pragma unroll
    for (int j = 0; j < 4; ++j) {
      const int idx = base + i * 4 + j;
      if (idx < NN) { run += vals[j]; off[idx + 1] = run; }
    }
  }
}

// ------------- K6b: fill CSR (rows bucketed by col) -------------
__global__ __launch_bounds__(256)
void k6b_fill(const int* __restrict__ ei, const int* __restrict__ coff,
              int* __restrict__ cursor, int* __restrict__ crow) {
  const int e = blockIdx.x * 256 + threadIdx.x;
  const int r = ei[e], c = ei[EE + e];
  const int pos = atomicAdd(&cursor[c], 1);
  crow[coff[c] + pos] = r;
}

// ------------- K7: gather-aggregate relational bias (bf16 v), zbuf += sig(b)*agg -------------
__global__ __launch_bounds__(256)
void k7_gather(const int* __restrict__ coff, const int* __restrict__ crow,
               const int* __restrict__ douti, const ushort_t* __restrict__ vb16,
               const float* __restrict__ bp, float* __restrict__ zbuf) {
  const int n = blockIdx.x;
  const int c = threadIdx.x;
  const int o0 = coff[n], o1 = coff[n + 1];
  float acc = 0.f;
  if (o1 > o0) {
    const float rin = rsqrtf((float)(o1 - o0));
    for (int e = o0; e < o1; ++e) {
      const int r = crow[e];
      const float w = rin * rsqrtf((float)douti[r]);
      acc = fmaf(w, b2f(vb16[(size_t)r * 256 + c]), acc);
    }
  }
  const float sb = 1.f / (1.f + expf(-bp[c >> 6]));
  zbuf[(size_t)n * 256 + c] += sb * acc;
}

// ------------- K8: out = zbuf @ Wo^T + bo -------------
__global__ __launch_bounds__(256)
void k8_out(const float* __restrict__ zbuf, const float* __restrict__ Wo,
            const float* __restrict__ bo, float* __restrict__ out) {
  __shared__ float WoT[256 * 33];
  __shared__ float zbl[8 * 256];
  const int t = threadIdx.x;
  const int ch = blockIdx.y;  // 0/1 -> output cols [ch*32, ch*32+32)
#pragma unroll
  for (int l = 0; l < 32; ++l) {
    WoT[t * 33 + l] = Wo[(ch * 32 + l) * 256 + t];
  }
  const int nl = t >> 5, cp = t & 31;
  const float bias = bo[ch * 32 + cp];
  for (int g = blockIdx.x; g < 2500; g += gridDim.x) {
    __syncthreads();
#pragma unroll
    for (int l = 0; l < 2; ++l) {
      const int f4 = l * 256 + t;
      *(float4*)&zbl[f4 * 4] = *(const float4*)(zbuf + (size_t)g * 2048 + f4 * 4);
    }
    __syncthreads();
    float acc = bias;
#pragma unroll
    for (int i4 = 0; i4 < 64; ++i4) {
      const float4 z4 = *(const float4*)&zbl[nl * 256 + i4 * 4];
      acc = fmaf(z4.x, WoT[(i4 * 4 + 0) * 33 + cp], acc);
      acc = fmaf(z4.y, WoT[(i4 * 4 + 1) * 33 + cp], acc);
      acc = fmaf(z4.z, WoT[(i4 * 4 + 2) * 33 + cp], acc);
      acc = fmaf(z4.w, WoT[(i4 * 4 + 3) * 33 + cp], acc);
    }
    out[((size_t)g * 8 + nl) * 64 + ch * 32 + cp] = acc;
  }
}

extern "C" void kernel_launch(void* const* d_in, const int* in_sizes, int n_in,
                              void* d_out, int out_size, void* d_ws, size_t ws_size,
                              hipStream_t stream) {
  (void)in_sizes; (void)n_in; (void)out_size; (void)ws_size;
  const float* z    = (const float*)d_in[0];
  const float* feat = (const float*)d_in[1];
  const int*   ei   = (const int*)d_in[2];
  const float* tau  = (const float*)d_in[3];
  const float* Wq_w = (const float*)d_in[4];
  const float* Wq_b = (const float*)d_in[5];
  const float* Wk_w = (const float*)d_in[6];
  const float* Wk_b = (const float*)d_in[7];
  const float* Wv_w = (const float*)d_in[8];
  const float* Wv_b = (const float*)d_in[9];
  const float* Wo_w = (const float*)d_in[10];
  const float* Wo_b = (const float*)d_in[11];
  const float* bp   = (const float*)d_in[12];
  const float* proj = (const float*)d_in[13];
  float* out = (float*)d_out;

  char* p = (char*)d_ws;
  auto alloc = [&](size_t bytes) { char* r = p; p += (bytes + 255) & ~(size_t)255; return r; };
  ushort_t* Wh    = (ushort_t*)alloc((size_t)256 * 1024 * 2);
  ushort_t* Wl    = (ushort_t*)alloc((size_t)256 * 1024 * 2);
  float*    bbig  = (float*)alloc(1024 * 4);
  ushort_t* vb16  = (ushort_t*)alloc((size_t)NN * 256 * 2);
  float*    qp    = (float*)alloc((size_t)NN * 120 * 4);
  float*    kbuf  = (float*)alloc((size_t)NN * 120 * 4);
  float*    zbuf  = (float*)alloc((size_t)NN * 256 * 4);
  // ---- contiguous zero-region ----
  char* z0 = p;
  float*    kvs   = (float*)alloc(7680 * 4);
  float*    ksum  = (float*)alloc(120 * 4);
  unsigned* kmaxU = (unsigned*)alloc(16);
  int*      dini  = (int*)alloc((size_t)20480 * 4);   // padded for int4 scan
  int*      douti = (int*)alloc((size_t)NN * 4);
  int*      cursor= (int*)alloc((size_t)NN * 4);
  char* z1 = p;
  int*      coff  = (int*)alloc((size_t)(NN + 1) * 4);
  int*      crow  = (int*)alloc((size_t)EE * 4);

  hipMemsetAsync(z0, 0, (size_t)(z1 - z0), stream);

  k0_build<<<1024, 256, 0, stream>>>(Wq_w, Wk_w, Wv_w, Wq_b, Wk_b, Wv_b, proj, tau, Wh, Wl, bbig);
  k5_deg<<<(EE / 4 + 255) / 256, 256, 0, stream>>>(ei, dini, douti);
  k6a_scan<<<1, 1024, 0, stream>>>(dini, coff);
  k6b_fill<<<EE / 256, 256, 0, stream>>>(ei, coff, cursor, crow);
  k1_mfma<<<157, 256, 0, stream>>>(feat, z, Wh, Wl, bbig, tau, qp, kbuf, vb16, kmaxU);
  k3_kvs<<<dim3((NN + 127) / 128, 4), 256, 0, stream>>>(kbuf, vb16, kmaxU, kvs, ksum);
  k4_attn<<<NN / 32, 256, 0, stream>>>(qp, kvs, ksum, zbuf);
  k7_gather<<<NN, 256, 0, stream>>>(coff, crow, douti, vb16, bp, zbuf);
  k8_out<<<dim3(512, 2), 256, 0, stream>>>(zbuf, Wo_w, Wo_b, out);
}